// Round 2
// baseline (1746.416 us; speedup 1.0000x reference)
//
#include <hip/hip_runtime.h>

// GCN layer: h = x @ W^T + b  [16384,128];  out = A_hat @ h  [16384,128]
// bf16 MFMA for both GEMMs (no fp32 MFMA on CDNA4), in-register fp32->bf16
// conversion. LDS-free, barrier-free streaming loops.
//
// hT (the intermediate, bf16) is stored PRE-SWIZZLED in MFMA B-fragment
// order so gemm2's B loads are single contiguous dwordx4 per wave:
//   element (o, n):  chunk = (n>>5)*8 + (o>>4)          (chunk = 1 KiB)
//   in-chunk short idx = ((n>>3)&3)*128 + (o&15)*8 + (n&7)
//   => lane (quad=(n>>3)&3, l16=o&15) reads 16 B at chunk_base + lane*16.

#define N_NODES 16384
#define IN_DIM  256
#define OUT_DIM 128

typedef short bf16x8 __attribute__((ext_vector_type(8)));
typedef float f32x4  __attribute__((ext_vector_type(4)));

// fp32 -> bf16 bits, round-to-nearest-even (inputs finite)
__device__ __forceinline__ unsigned short f2bf(float f) {
    unsigned u = __float_as_uint(f);
    u += 0x7fffu + ((u >> 16) & 1u);
    return (unsigned short)(u >> 16);
}

__device__ __forceinline__ bf16x8 cvt8(f32x4 a, f32x4 c) {
    bf16x8 r;
#pragma unroll
    for (int i = 0; i < 4; ++i) {
        r[i]     = (short)f2bf(a[i]);
        r[i + 4] = (short)f2bf(c[i]);
    }
    return r;
}

// regular cached path (x, W)
__device__ __forceinline__ bf16x8 load_cvt8(const float* __restrict__ p) {
    return cvt8(*reinterpret_cast<const f32x4*>(p),
                *reinterpret_cast<const f32x4*>(p + 4));
}

// nontemporal path (A_hat: read exactly once; keep L2 for hT)
__device__ __forceinline__ bf16x8 load_cvt8_nt(const float* __restrict__ p) {
    f32x4 a = __builtin_nontemporal_load(reinterpret_cast<const f32x4*>(p));
    f32x4 c = __builtin_nontemporal_load(reinterpret_cast<const f32x4*>(p) + 1);
    return cvt8(a, c);
}

// ---------------------------------------------------------------------------
// GEMM1: hT_swz(o,n) = sum_k W[o][k] * x[n][k] + b[o]
// Block: 256 thr = 4 waves (2 o x 2 n), tile 128(o) x 64(n); wave 64o x 32n
// Grid = 16384/64 = 256 blocks (1 per CU).
// ---------------------------------------------------------------------------
__global__ __launch_bounds__(256) void gemm1_xw(
    const float* __restrict__ x, const float* __restrict__ W,
    const float* __restrict__ b, unsigned short* __restrict__ hT) {
    const int tid  = threadIdx.x;
    const int lane = tid & 63, wid = tid >> 6;
    const int l16  = lane & 15, quad = lane >> 4;
    const int n0   = blockIdx.x * 64;
    const int wm   = (wid >> 1) * 64;   // o-offset of wave
    const int wn   = (wid & 1) * 32;    // n-offset of wave

    f32x4 acc[4][2] = {};

    const float* aBase = W + (size_t)(wm + l16) * IN_DIM + quad * 8;
    const float* bBase = x + (size_t)(n0 + wn + l16) * IN_DIM + quad * 8;

#pragma unroll 2
    for (int k = 0; k < IN_DIM; k += 32) {
        bf16x8 af[4], bfr[2];
#pragma unroll
        for (int mf = 0; mf < 4; ++mf)
            af[mf] = load_cvt8(aBase + (size_t)mf * 16 * IN_DIM + k);
#pragma unroll
        for (int nf = 0; nf < 2; ++nf)
            bfr[nf] = load_cvt8(bBase + (size_t)nf * 16 * IN_DIM + k);
#pragma unroll
        for (int mf = 0; mf < 4; ++mf)
#pragma unroll
            for (int nf = 0; nf < 2; ++nf)
                acc[mf][nf] = __builtin_amdgcn_mfma_f32_16x16x32_bf16(
                    af[mf], bfr[nf], acc[mf][nf], 0, 0, 0);
    }

    // C/D layout: col(n) = l16, row(o) = quad*4 + i ; write into swizzled hT
#pragma unroll
    for (int mf = 0; mf < 4; ++mf) {
#pragma unroll
        for (int i = 0; i < 4; ++i) {
            const int o    = wm + mf * 16 + quad * 4 + i;
            const float bo = b[o];
#pragma unroll
            for (int nf = 0; nf < 2; ++nf) {
                const int n = n0 + wn + nf * 16 + l16;
                const size_t idx = (size_t)((n >> 5) * 8 + (o >> 4)) * 512
                                 + ((n >> 3) & 3) * 128 + (o & 15) * 8 + (n & 7);
                hT[idx] = f2bf(acc[mf][nf][i] + bo);
            }
        }
    }
}

// ---------------------------------------------------------------------------
// GEMM2: out[m][o] = sum_j A_hat[m][j] * hT(o,j)
// Block: 256 thr = 4 waves (2 m x 2 o), tile 32(m) x 128(o); wave 16m x 64o
// Grid = 16384/32 = 512 blocks = 2 blocks/CU = 2 waves/SIMD.
// A: nontemporal fp32 streams (1.07 GB -> the HBM roofline).
// hT: L2-resident, swizzled -> single contiguous dwordx4 per B-frag.
// ---------------------------------------------------------------------------
__global__ __launch_bounds__(256) void gemm2_ah(
    const float* __restrict__ A, const unsigned short* __restrict__ hT,
    float* __restrict__ out) {
    const int tid  = threadIdx.x;
    const int lane = tid & 63, wid = tid >> 6;
    const int l16  = lane & 15, quad = lane >> 4;
    const int m0   = blockIdx.x * 32;
    const int wm   = (wid >> 1) * 16;
    const int wn   = (wid & 1) * 64;
    const int otile = wn >> 4;          // 0 or 4

    f32x4 acc[4] = {};

    const float*          aBase = A  + (size_t)(m0 + wm + l16) * N_NODES + quad * 8;
    const unsigned short* bBase = hT + (size_t)lane * 8 + (size_t)otile * 512;

#pragma unroll 4
    for (int k = 0; k < N_NODES; k += 32) {
        bf16x8 af = load_cvt8_nt(aBase + k);
        const unsigned short* bk = bBase + (size_t)(k >> 5) * 4096;
        bf16x8 bfr[4];
#pragma unroll
        for (int nf = 0; nf < 4; ++nf)
            bfr[nf] = *reinterpret_cast<const bf16x8*>(bk + nf * 512);
#pragma unroll
        for (int nf = 0; nf < 4; ++nf)
            acc[nf] = __builtin_amdgcn_mfma_f32_16x16x32_bf16(
                af, bfr[nf], acc[nf], 0, 0, 0);
    }

#pragma unroll
    for (int i = 0; i < 4; ++i) {
        const int row = m0 + wm + quad * 4 + i;
#pragma unroll
        for (int nf = 0; nf < 4; ++nf) {
            const int col = wn + nf * 16 + l16;
            __builtin_nontemporal_store(acc[nf][i],
                                        out + (size_t)row * OUT_DIM + col);
        }
    }
}

extern "C" void kernel_launch(void* const* d_in, const int* in_sizes, int n_in,
                              void* d_out, int out_size, void* d_ws, size_t ws_size,
                              hipStream_t stream) {
    const float* x     = (const float*)d_in[0];
    const float* A_hat = (const float*)d_in[1];
    const float* W     = (const float*)d_in[2];
    const float* b     = (const float*)d_in[3];
    float* out         = (float*)d_out;
    unsigned short* hT = (unsigned short*)d_ws;  // 4 MB swizzled intermediate

    gemm1_xw<<<N_NODES / 64, 256, 0, stream>>>(x, W, b, hT);
    gemm2_ah<<<N_NODES / 32, 256, 0, stream>>>(A_hat, hT, out);
}